// Round 11
// baseline (547.411 us; speedup 1.0000x reference)
//
#include <hip/hip_runtime.h>
#include <type_traits>

// TGV prox primal-dual, 30 iterations on (3,512,512) fp32.
// R11: ROW-PAIR THREADS — each interior thread owns 2 adjacent rows x 4 cols.
// u-stencil rows {r0-1, r0, r1, r1+1} = 14 segment loads per pair vs 20 for
// two independent threads (-30% u-loads, the proven lever: R8 mask-ALU -6.6%,
// R9 load-count/addr-chains -12.6%; R10 ring/ds_read cuts -1% => critical
// path = stage-1 u-gather VMEM chain). Row r1's N-arrays = row r0's C-arrays
// (already converted); r0's S-row = r1's C-row. Bit-identical arithmetic.
// Dropped R10's xbar reg-reuse (proven null) to keep cross-barrier state
// small. Block 192 = 128 pair-interior + 52 ring (top/bot single rows,
// left/right col-pairs). Grid (8,32,3)=768.
// Frozen: x2 fp32 / r,u fp16 interleaved ping-pong, single barrier, rsqrt
// projections, SAFE/edge block split, 30 launches.
// R3: never grid.sync on this chip (~200us/iter).

#define H 512
#define W 512
#define C 3
#define HW (H * W)
#define CHW (C * H * W)
#define N_IT 30

#define TW 64
#define TH 16

#define TAU     0.01f
#define LAM2    0.15f
#define RHO     1.99f
#define SIGMA   1.3888888888888888f   /* 1/TAU/72 */
#define TL1     0.001f                /* TAU*LAM1 */
#define INV_1PT (1.0f / 1.01f)        /* 1/(1+TAU) */

// xbar/rbar planes rows -1..16 (18), cols lc = col+4 (col -4..67)
#define BROWS 18
#define BSTR  72

typedef _Float16 f16;
typedef __attribute__((ext_vector_type(4))) _Float16 h4;   //  8B (one pixel quad)
typedef __attribute__((ext_vector_type(8))) _Float16 h8;   // 16B (two pixel quads)

// h-buffer layout (f16 units): [0, 2*CHW) = r interleaved (r0,r1) per pixel;
//                              [2*CHW, 6*CHW) = u interleaved (u0..u3) per pixel.

template <int MODE> // 0 = first iter, 1 = middle, 2 = last (dst = d_out interleaved)
__global__ __launch_bounds__(192)
void fused_it(const float* __restrict__ y,
              const float* __restrict__ srcX,
              const f16*   __restrict__ srcH,
              float*       __restrict__ dstX,
              f16*         __restrict__ dstH,
              float*       __restrict__ outp)
{
    __shared__ float sb[3][BROWS][BSTR]; // 0=xbar 1=rbar0 2=rbar1

    const int tid = threadIdx.x;
    const int c   = blockIdx.z;
    const int i0  = blockIdx.y * TH;
    const int j0  = blockIdx.x * TW;
    const int cb  = c * HW;

    const bool edge = (MODE == 0) ||
                      (blockIdx.x == 0) || (blockIdx.x == W / TW - 1) ||
                      (blockIdx.y == 0) || (blockIdx.y == H / TH - 1);

    const f16* rSrc = srcH;            // (r0,r1) pairs
    const f16* uSrc = srcH + 2 * CHW;  // (u0..u3) quads
    f16* rDst = dstH;
    f16* uDst = dstH ? dstH + 2 * CHW : nullptr;

    // center-u stash across the barrier (slot A = row r0, slot B = row r1)
    float cu0A[4], cu1A[4], cu2A[4], cu3A[4];
    float cu0B[4], cu1B[4], cu2B[4], cu3B[4];

    // ---- prox + sb-write + optional global store (masks only when !SAFE) ----
    auto s1finish = [&](auto SAFE_c, int gi, int gjb, int p, int lrow, bool interior,
                        const float* yv, const float* x2c, const float* r0c, const float* r1c,
                        const float* t0c, const float* t1c, const float* t0n, const float* t1w) {
        constexpr bool SAFE = decltype(SAFE_c)::value;
        const int s4 = gjb - j0 + 4;
        const bool imH = SAFE ? true : (gi < H - 1);
        float xb[4], rb0[4], rb1[4], xnew[4], rn0[4], rn1[4];
        #pragma unroll
        for (int e = 0; e < 4; ++e) {
            const int gj = gjb + e;
            const bool jmW = SAFE ? true : (gj < W - 1);
            const float nT  = t0n[e] - (imH ? t0c[e] : 0.f) + t1w[e] - (jmW ? t1c[e] : 0.f);
            const float xv  = (x2c[e] - nT + TAU * yv[e]) * INV_1PT;
            xb[e] = 2.f * xv - x2c[e];
            const float rp0 = r0c[e] + t0c[e];
            const float rp1 = r1c[e] + t1c[e];
            const float ss  = rp0 * rp0 + rp1 * rp1;
            const float f   = 1.f - fminf(TL1 * rsqrtf(ss), 1.f);
            const float rv0 = rp0 * f, rv1 = rp1 * f;
            rb0[e]  = 2.f * rv0 - r0c[e];
            rb1[e]  = 2.f * rv1 - r1c[e];
            xnew[e] = x2c[e] + RHO * (xv - x2c[e]);
            rn0[e]  = r0c[e] + RHO * (rv0 - r0c[e]);
            rn1[e]  = r1c[e] + RHO * (rv1 - r1c[e]);
        }
        *(float4*)&sb[0][lrow][s4] = *(float4*)xb;
        *(float4*)&sb[1][lrow][s4] = *(float4*)rb0;
        *(float4*)&sb[2][lrow][s4] = *(float4*)rb1;

        if (interior) {
            if (MODE == 2) {
                *(float4*)(outp + p) = *(float4*)xnew;
                *(float4*)(outp + CHW + 2 * p)     = make_float4(rn0[0], rn1[0], rn0[1], rn1[1]);
                *(float4*)(outp + CHW + 2 * p + 4) = make_float4(rn0[2], rn1[2], rn0[3], rn1[3]);
            } else {
                *(float4*)(dstX + p) = *(float4*)xnew;
                h8 hr;
                #pragma unroll
                for (int e = 0; e < 4; ++e) {
                    hr[2 * e]     = (f16)rn0[e];
                    hr[2 * e + 1] = (f16)rn1[e];
                }
                *(h8*)(rDst + 2 * p) = hr;
            }
        }
    };

    auto tSafe = [&](const float* u0c, const float* u1c, const float* u2r, const float* u3c,
                     const float* u0n, const float* u1n, const float* u3n, const float* u0s,
                     float* t0c, float* t1c, float* t0n, float* t1w) {
        #pragma unroll
        for (int e = 0; e < 4; ++e) {
            t0c[e] = TAU * (u0c[e] - u0s[e] + u1c[e] - u1c[e + 1]);
            t1c[e] = TAU * (u2r[e + 1] - u2r[e + 2] + u3n[e + 1] - u3c[e + 1]);
            t0n[e] = TAU * (u0n[e] - u0c[e] + u1n[e] - u1n[e + 1]);
            t1w[e] = TAU * (u2r[e] - u2r[e + 1] + u3n[e] - u3c[e]);
        }
    };

    auto U4 = [&](int pp) { return *(const h4*)(uSrc + 4 * pp); };
    auto U8 = [&](int pp) { return *(const h8*)(uSrc + 4 * pp); };

    // ---- SAFE pair: stage-1 for rows r0, r0+1 sharing the u-stencil ----
    auto pairSafe = [&](int r0, int s, bool interior) {
        const int gi0 = i0 + r0, gjb = j0 + s;
        const int p0 = cb + gi0 * W + gjb, pN = p0 - W, p1 = p0 + W, pS = p1 + W;

        float yv0[4], yv1[4], x20[4], x21[4], r00[4], r01v[4], r10[4], r11v[4];
        *(float4*)yv0 = *(const float4*)(y + p0);
        *(float4*)yv1 = *(const float4*)(y + p1);
        *(float4*)x20 = *(const float4*)(srcX + p0);
        *(float4*)x21 = *(const float4*)(srcX + p1);
        {
            const h8 rv = *(const h8*)(rSrc + 2 * p0);
            #pragma unroll
            for (int e = 0; e < 4; ++e) { r00[e] = (float)rv[2 * e]; r10[e] = (float)rv[2 * e + 1]; }
        }
        {
            const h8 rv = *(const h8*)(rSrc + 2 * p1);
            #pragma unroll
            for (int e = 0; e < 4; ++e) { r01v[e] = (float)rv[2 * e]; r11v[e] = (float)rv[2 * e + 1]; }
        }
        // 14 u segment loads for 2 rows (vs 20 unshared)
        const h4 nA = U4(pN - 1); const h8 nB = U8(pN), nC = U8(pN + 2); const h4 nD = U4(pN + 4);
        const h4 aA = U4(p0 - 1); const h8 aB = U8(p0), aC = U8(p0 + 2); const h4 aD = U4(p0 + 4);
        const h4 bA = U4(p1 - 1); const h8 bB = U8(p1), bC = U8(p1 + 2); const h4 bD = U4(p1 + 4);
        const h8 sB = U8(pS), sC = U8(pS + 2);

        const float N0[4] = {(float)nB[0], (float)nB[4], (float)nC[0], (float)nC[4]};
        const float N1[5] = {(float)nB[1], (float)nB[5], (float)nC[1], (float)nC[5], (float)nD[1]};
        const float N3[5] = {(float)nA[3], (float)nB[3], (float)nB[7], (float)nC[3], (float)nC[7]};
        const float A0[4] = {(float)aB[0], (float)aB[4], (float)aC[0], (float)aC[4]};
        const float A1[5] = {(float)aB[1], (float)aB[5], (float)aC[1], (float)aC[5], (float)aD[1]};
        const float A2[6] = {(float)aA[2], (float)aB[2], (float)aB[6], (float)aC[2], (float)aC[6], (float)aD[2]};
        const float A3[5] = {(float)aA[3], (float)aB[3], (float)aB[7], (float)aC[3], (float)aC[7]};
        const float B0[4] = {(float)bB[0], (float)bB[4], (float)bC[0], (float)bC[4]};
        const float B1[5] = {(float)bB[1], (float)bB[5], (float)bC[1], (float)bC[5], (float)bD[1]};
        const float B2[6] = {(float)bA[2], (float)bB[2], (float)bB[6], (float)bC[2], (float)bC[6], (float)bD[2]};
        const float B3[5] = {(float)bA[3], (float)bB[3], (float)bB[7], (float)bC[3], (float)bC[7]};
        const float S0[4] = {(float)sB[0], (float)sB[4], (float)sC[0], (float)sC[4]};

        float t0c[4], t1c[4], t0n[4], t1w[4];
        // row r0: C = A-arrays, N = N-arrays, S(u0s) = B0
        tSafe(A0, A1, A2, A3, N0, N1, N3, B0, t0c, t1c, t0n, t1w);
        if (interior) {
            #pragma unroll
            for (int e = 0; e < 4; ++e) {
                cu0A[e] = A0[e]; cu1A[e] = A1[e]; cu2A[e] = A2[e + 1]; cu3A[e] = A3[e + 1];
            }
        }
        s1finish(std::true_type{}, gi0, gjb, p0, r0 + 1, interior, yv0, x20, r00, r10,
                 t0c, t1c, t0n, t1w);
        // row r1: C = B-arrays, N = A-arrays (free), S(u0s) = S0
        tSafe(B0, B1, B2, B3, A0, A1, A3, S0, t0c, t1c, t0n, t1w);
        if (interior) {
            #pragma unroll
            for (int e = 0; e < 4; ++e) {
                cu0B[e] = B0[e]; cu1B[e] = B1[e]; cu2B[e] = B2[e + 1]; cu3B[e] = B3[e + 1];
            }
        }
        s1finish(std::true_type{}, gi0 + 1, gjb, p1, r0 + 2, interior, yv1, x21, r01v, r11v,
                 t0c, t1c, t0n, t1w);
    };

    // ---- SAFE single row (ring top/bottom) ----
    auto singleSafe = [&](int rr, int s) {
        const int gi = i0 + rr, gjb = j0 + s;
        const int p = cb + gi * W + gjb, pN = p - W, pS = p + W;
        float yv[4], x2c[4], r0c[4], r1c[4];
        *(float4*)yv  = *(const float4*)(y + p);
        *(float4*)x2c = *(const float4*)(srcX + p);
        {
            const h8 rv = *(const h8*)(rSrc + 2 * p);
            #pragma unroll
            for (int e = 0; e < 4; ++e) { r0c[e] = (float)rv[2 * e]; r1c[e] = (float)rv[2 * e + 1]; }
        }
        const h4 nA = U4(pN - 1); const h8 nB = U8(pN), nC = U8(pN + 2); const h4 nD = U4(pN + 4);
        const h4 cA = U4(p - 1);  const h8 cB = U8(p),  cC = U8(p + 2);  const h4 cD = U4(p + 4);
        const h8 sB = U8(pS), sC = U8(pS + 2);

        const float u0c[4] = {(float)cB[0], (float)cB[4], (float)cC[0], (float)cC[4]};
        const float u1c[5] = {(float)cB[1], (float)cB[5], (float)cC[1], (float)cC[5], (float)cD[1]};
        const float u2r[6] = {(float)cA[2], (float)cB[2], (float)cB[6], (float)cC[2], (float)cC[6], (float)cD[2]};
        const float u3c[5] = {(float)cA[3], (float)cB[3], (float)cB[7], (float)cC[3], (float)cC[7]};
        const float u0n[4] = {(float)nB[0], (float)nB[4], (float)nC[0], (float)nC[4]};
        const float u1n[5] = {(float)nB[1], (float)nB[5], (float)nC[1], (float)nC[5], (float)nD[1]};
        const float u3n[5] = {(float)nA[3], (float)nB[3], (float)nB[7], (float)nC[3], (float)nC[7]};
        const float u0s[4] = {(float)sB[0], (float)sB[4], (float)sC[0], (float)sC[4]};

        float t0c[4], t1c[4], t0n[4], t1w[4];
        tSafe(u0c, u1c, u2r, u3c, u0n, u1n, u3n, u0s, t0c, t1c, t0n, t1w);
        s1finish(std::true_type{}, gi, gjb, p, rr + 1, false, yv, x2c, r0c, r1c,
                 t0c, t1c, t0n, t1w);
    };

    // ---- edge single row (full masks; also handles MODE 0) ----
    auto edgeRow = [&](int rr, int s, bool interior,
                       float* cu0s, float* cu1s, float* cu2s, float* cu3s) {
        const int gi  = i0 + rr;
        const int gjb = j0 + s;
        const int p   = cb + gi * W + gjb;
        const bool rowC  = (unsigned)gi < H;
        const bool cMain = (unsigned)gjb < W;
        const bool okC   = rowC && cMain;

        float yv[4], x2c[4], r0c[4], r1c[4];
        if (okC) {
            *(float4*)yv = *(const float4*)(y + p);
        } else {
            yv[0] = yv[1] = yv[2] = yv[3] = 0.f;
        }
        if (MODE != 0) {
            if (okC) {
                *(float4*)x2c = *(const float4*)(srcX + p);
                const h8 rv = *(const h8*)(rSrc + 2 * p);
                #pragma unroll
                for (int e = 0; e < 4; ++e) { r0c[e] = (float)rv[2 * e]; r1c[e] = (float)rv[2 * e + 1]; }
            } else {
                #pragma unroll
                for (int e = 0; e < 4; ++e) { x2c[e] = 0.f; r0c[e] = 0.f; r1c[e] = 0.f; }
            }
        }

        float t0c[4], t1c[4], t0n[4], t1w[4];
        if (MODE == 0) {
            #pragma unroll
            for (int e = 0; e < 4; ++e) {
                x2c[e] = yv[e]; r0c[e] = 0.f; r1c[e] = 0.f;
                t0c[e] = t1c[e] = t0n[e] = t1w[e] = 0.f;
            }
            if (interior) {
                #pragma unroll
                for (int e = 0; e < 4; ++e) { cu0s[e] = cu1s[e] = cu2s[e] = cu3s[e] = 0.f; }
            }
        } else {
            const bool rowN = (unsigned)(gi - 1) < H;
            const bool rowS = (unsigned)(gi + 1) < H;
            const bool cm1  = (unsigned)(gjb - 1) < W;
            const bool c4   = (unsigned)(gjb + 4) < W;
            const int pN = p - W, pS = p + W;

            auto L4 = [&](int pp, bool ok) -> h4 {
                h4 z = {}; if (ok) z = *(const h4*)(uSrc + 4 * pp); return z;
            };
            auto L8 = [&](int pp, bool ok) -> h8 {
                h8 z = {}; if (ok) z = *(const h8*)(uSrc + 4 * pp); return z;
            };
            const h4 nA = L4(pN - 1, rowN && cm1);
            const h8 nB = L8(pN,     rowN && cMain);
            const h8 nC = L8(pN + 2, rowN && cMain);
            const h4 nD = L4(pN + 4, rowN && c4);
            const h4 cA = L4(p - 1,  rowC && cm1);
            const h8 cB = L8(p,      okC);
            const h8 cC = L8(p + 2,  okC);
            const h4 cD = L4(p + 4,  rowC && c4);
            const h8 sB = L8(pS,     rowS && cMain);
            const h8 sC = L8(pS + 2, rowS && cMain);

            const float u0c[4] = {(float)cB[0], (float)cB[4], (float)cC[0], (float)cC[4]};
            const float u1c[5] = {(float)cB[1], (float)cB[5], (float)cC[1], (float)cC[5], (float)cD[1]};
            const float u2r[6] = {(float)cA[2], (float)cB[2], (float)cB[6], (float)cC[2], (float)cC[6], (float)cD[2]};
            const float u3c[5] = {(float)cA[3], (float)cB[3], (float)cB[7], (float)cC[3], (float)cC[7]};
            const float u0n[4] = {(float)nB[0], (float)nB[4], (float)nC[0], (float)nC[4]};
            const float u1n[5] = {(float)nB[1], (float)nB[5], (float)nC[1], (float)nC[5], (float)nD[1]};
            const float u3n[5] = {(float)nA[3], (float)nB[3], (float)nB[7], (float)nC[3], (float)nC[7]};
            const float u0s[4] = {(float)sB[0], (float)sB[4], (float)sC[0], (float)sC[4]};

            const bool im0 = gi > 0, imHl = gi < H - 1;
            #pragma unroll
            for (int e = 0; e < 4; ++e) {
                const int gj = gjb + e;
                const bool jm0 = gj > 0;
                t0c[e] = TAU * (u0c[e] - u0s[e] + (jm0 ? u1c[e] : 0.f) - u1c[e + 1]);
                t1c[e] = TAU * (u2r[e + 1] - u2r[e + 2] + u3n[e + 1] - (imHl ? u3c[e + 1] : 0.f));
                t0n[e] = im0 ? TAU * (u0n[e] - u0c[e] + (jm0 ? u1n[e] : 0.f) - u1n[e + 1]) : 0.f;
                t1w[e] = jm0 ? TAU * (u2r[e] - u2r[e + 1] + u3n[e] - (imHl ? u3c[e] : 0.f)) : 0.f;
            }
            if (interior) {
                #pragma unroll
                for (int e = 0; e < 4; ++e) {
                    cu0s[e] = u0c[e]; cu1s[e] = u1c[e];
                    cu2s[e] = u2r[e + 1]; cu3s[e] = u3c[e + 1];
                }
            }
        }
        s1finish(std::false_type{}, gi, gjb, p, rr + 1, interior, yv, x2c, r0c, r1c,
                 t0c, t1c, t0n, t1w);
    };

    // ---- stage-1 dispatch ----
    if (!edge) {
        if (tid < 128) {
            pairSafe(2 * (tid >> 4), 4 * (tid & 15), true);
        } else if (tid < 180) {
            const int t = tid - 128;
            if (t < 18)      singleSafe(-1, 4 * t - 4);
            else if (t < 36) singleSafe(TH, 4 * (t - 18) - 4);
            else if (t < 44) pairSafe(2 * (t - 36), -4, false);
            else             pairSafe(2 * (t - 44), TW, false);
        }
    } else {
        if (tid < 128) {
            const int r0v = 2 * (tid >> 4), sv = 4 * (tid & 15);
            edgeRow(r0v,     sv, true, cu0A, cu1A, cu2A, cu3A);
            edgeRow(r0v + 1, sv, true, cu0B, cu1B, cu2B, cu3B);
        } else if (tid < 180) {
            const int t = tid - 128;
            if (t < 18)      edgeRow(-1, 4 * t - 4, false, cu0A, cu1A, cu2A, cu3A);
            else if (t < 36) edgeRow(TH, 4 * (t - 18) - 4, false, cu0A, cu1A, cu2A, cu3A);
            else if (t < 44) {
                edgeRow(2 * (t - 36),     -4, false, cu0A, cu1A, cu2A, cu3A);
                edgeRow(2 * (t - 36) + 1, -4, false, cu0A, cu1A, cu2A, cu3A);
            } else {
                edgeRow(2 * (t - 44),     TW, false, cu0A, cu1A, cu2A, cu3A);
                edgeRow(2 * (t - 44) + 1, TW, false, cu0A, cu1A, cu2A, cu3A);
            }
        }
    }
    __syncthreads(); // the ONLY barrier: xbar/rbar handoff

    // ---- stage-2 row core ----
    auto s2row = [&](auto SAFE_c, int gi, int gjb, int p,
                     const float* xA, const float* xS, const float* xN,
                     const float* r0C, const float* r0N, const float* r1C, const float* r1S,
                     const float* cu0s, const float* cu1s, const float* cu2s, const float* cu3s) {
        constexpr bool SAFE = decltype(SAFE_c)::value;
        const bool im0 = SAFE ? true : (gi > 0);
        const bool imH = SAFE ? true : (gi < H - 1);
        float un0[4], un1[4], un2[4], un3[4];
        #pragma unroll
        for (int e = 0; e < 4; ++e) {
            const int gj = gjb + e;
            const bool jm0 = SAFE ? true : (gj > 0);
            const bool jmW = SAFE ? true : (gj < W - 1);
            const float xC = xA[e + 1], xE = xA[e + 2], xW_ = xA[e];
            const float I0c = (imH ? xS[e + 1] - xC : 0.f) - r0C[e + 1];
            const float I0n = im0 ? (xC - xN[e] - r0N[e]) : 0.f;
            const float I0w = jm0 ? ((imH ? xS[e] - xW_ : 0.f) - r0C[e]) : 0.f;
            const float I1c = (jmW ? xE - xC : 0.f) - r1C[e + 1];
            const float I1w = jm0 ? (xC - xW_ - r1C[e]) : 0.f;
            const float I1s = imH ? ((jmW ? xS[e + 2] - xS[e + 1] : 0.f) - r1S[e]) : 0.f;
            const float g0 = I0c - I0n;
            const float g1 = jm0 ? (I0c - I0w) : 0.f;
            const float g2 = I1c - I1w;
            const float g3 = imH ? (I1s - I1c) : 0.f;
            const float up0 = cu0s[e] + SIGMA * g0;
            const float up1 = cu1s[e] + SIGMA * g1;
            const float up2 = cu2s[e] + SIGMA * g2;
            const float up3 = cu3s[e] + SIGMA * g3;
            const float ss  = up0 * up0 + up1 * up1 + up2 * up2 + up3 * up3;
            const float inv = fminf(LAM2 * rsqrtf(ss), 1.f);
            un0[e] = cu0s[e] + RHO * (up0 * inv - cu0s[e]);
            un1[e] = cu1s[e] + RHO * (up1 * inv - cu1s[e]);
            un2[e] = cu2s[e] + RHO * (up2 * inv - cu2s[e]);
            un3[e] = cu3s[e] + RHO * (up3 * inv - cu3s[e]);
        }
        if (MODE == 2) {
            #pragma unroll
            for (int e = 0; e < 4; ++e)
                *(float4*)(outp + 3 * CHW + 4 * (p + e)) =
                    make_float4(un0[e], un1[e], un2[e], un3[e]);
        } else {
            h8 w0, w1;
            #pragma unroll
            for (int e = 0; e < 2; ++e) {
                w0[4 * e + 0] = (f16)un0[e]; w0[4 * e + 1] = (f16)un1[e];
                w0[4 * e + 2] = (f16)un2[e]; w0[4 * e + 3] = (f16)un3[e];
            }
            #pragma unroll
            for (int e = 2; e < 4; ++e) {
                w1[4 * (e - 2) + 0] = (f16)un0[e]; w1[4 * (e - 2) + 1] = (f16)un1[e];
                w1[4 * (e - 2) + 2] = (f16)un2[e]; w1[4 * (e - 2) + 3] = (f16)un3[e];
            }
            *(h8*)(uDst + 4 * p)     = w0;
            *(h8*)(uDst + 4 * p + 8) = w1;
        }
    };

    if (tid < 128) {
        const int tx = tid & 15, q = tid >> 4;
        const int r0 = 2 * q;
        const int gi0 = i0 + r0, gjb = j0 + 4 * tx;
        const int p0 = cb + gi0 * W + gjb;
        const int lr0 = r0 + 1, lr1 = r0 + 2, lc = 4 * tx + 4;

        if (!edge) {
            float4 v;
            // plane 0 (xbar): rows lr0-1 .. lr1+1
            float xNr[4];
            v = *(const float4*)&sb[0][lr0 - 1][lc]; xNr[0]=v.x; xNr[1]=v.y; xNr[2]=v.z; xNr[3]=v.w;
            float xAr[6];
            xAr[0] = sb[0][lr0][lc - 1];
            v = *(const float4*)&sb[0][lr0][lc]; xAr[1]=v.x; xAr[2]=v.y; xAr[3]=v.z; xAr[4]=v.w;
            xAr[5] = sb[0][lr0][lc + 4];
            float xMr[6];
            xMr[0] = sb[0][lr1][lc - 1];
            v = *(const float4*)&sb[0][lr1][lc]; xMr[1]=v.x; xMr[2]=v.y; xMr[3]=v.z; xMr[4]=v.w;
            xMr[5] = sb[0][lr1][lc + 4];
            float xSr[6];
            xSr[0] = sb[0][lr1 + 1][lc - 1];
            v = *(const float4*)&sb[0][lr1 + 1][lc]; xSr[1]=v.x; xSr[2]=v.y; xSr[3]=v.z; xSr[4]=v.w;
            xSr[5] = sb[0][lr1 + 1][lc + 4];
            // plane 1 (rbar0)
            float r0Nr[4];
            v = *(const float4*)&sb[1][lr0 - 1][lc]; r0Nr[0]=v.x; r0Nr[1]=v.y; r0Nr[2]=v.z; r0Nr[3]=v.w;
            float r0Ca[5];
            r0Ca[0] = sb[1][lr0][lc - 1];
            v = *(const float4*)&sb[1][lr0][lc]; r0Ca[1]=v.x; r0Ca[2]=v.y; r0Ca[3]=v.z; r0Ca[4]=v.w;
            float r0Cb[5];
            r0Cb[0] = sb[1][lr1][lc - 1];
            v = *(const float4*)&sb[1][lr1][lc]; r0Cb[1]=v.x; r0Cb[2]=v.y; r0Cb[3]=v.z; r0Cb[4]=v.w;
            // plane 2 (rbar1)
            float r1Ca[5];
            r1Ca[0] = sb[2][lr0][lc - 1];
            v = *(const float4*)&sb[2][lr0][lc]; r1Ca[1]=v.x; r1Ca[2]=v.y; r1Ca[3]=v.z; r1Ca[4]=v.w;
            float r1Cb[5];
            r1Cb[0] = sb[2][lr1][lc - 1];
            v = *(const float4*)&sb[2][lr1][lc]; r1Cb[1]=v.x; r1Cb[2]=v.y; r1Cb[3]=v.z; r1Cb[4]=v.w;
            float r1Sr[4];
            v = *(const float4*)&sb[2][lr1 + 1][lc]; r1Sr[0]=v.x; r1Sr[1]=v.y; r1Sr[2]=v.z; r1Sr[3]=v.w;

            // row r0: S-row values come from row lr1 (shared); r1S = rbar1@lr1
            const float r1S0[4] = {r1Cb[1], r1Cb[2], r1Cb[3], r1Cb[4]};
            s2row(std::true_type{}, gi0, gjb, p0,
                  xAr, xMr, xNr, r0Ca, r0Nr, r1Ca, r1S0,
                  cu0A, cu1A, cu2A, cu3A);
            // row r1: N-row values come from row lr0 (shared)
            const float xN1[4]  = {xAr[1], xAr[2], xAr[3], xAr[4]};
            const float r0N1[4] = {r0Ca[1], r0Ca[2], r0Ca[3], r0Ca[4]};
            s2row(std::true_type{}, gi0 + 1, gjb, p0 + W,
                  xMr, xSr, xN1, r0Cb, r0N1, r1Cb, r1Sr,
                  cu0B, cu1B, cu2B, cu3B);
        } else {
            // edge: two independent masked rows, full LDS reads each
            #pragma unroll
            for (int slot = 0; slot < 2; ++slot) {
                const int rr = r0 + slot;
                const int gi = i0 + rr;
                const int lr = rr + 1;
                const int p  = cb + gi * W + gjb;
                float4 v;
                float xA[6], xS[6], xN[4], r0C[5], r0N[4], r1C[5], r1S[4];
                xA[0] = sb[0][lr][lc - 1];
                v = *(const float4*)&sb[0][lr][lc]; xA[1]=v.x; xA[2]=v.y; xA[3]=v.z; xA[4]=v.w;
                xA[5] = sb[0][lr][lc + 4];
                xS[0] = sb[0][lr + 1][lc - 1];
                v = *(const float4*)&sb[0][lr + 1][lc]; xS[1]=v.x; xS[2]=v.y; xS[3]=v.z; xS[4]=v.w;
                xS[5] = sb[0][lr + 1][lc + 4];
                v = *(const float4*)&sb[0][lr - 1][lc]; xN[0]=v.x; xN[1]=v.y; xN[2]=v.z; xN[3]=v.w;
                r0C[0] = sb[1][lr][lc - 1];
                v = *(const float4*)&sb[1][lr][lc]; r0C[1]=v.x; r0C[2]=v.y; r0C[3]=v.z; r0C[4]=v.w;
                v = *(const float4*)&sb[1][lr - 1][lc]; r0N[0]=v.x; r0N[1]=v.y; r0N[2]=v.z; r0N[3]=v.w;
                r1C[0] = sb[2][lr][lc - 1];
                v = *(const float4*)&sb[2][lr][lc]; r1C[1]=v.x; r1C[2]=v.y; r1C[3]=v.z; r1C[4]=v.w;
                v = *(const float4*)&sb[2][lr + 1][lc]; r1S[0]=v.x; r1S[1]=v.y; r1S[2]=v.z; r1S[3]=v.w;
                if (slot == 0)
                    s2row(std::false_type{}, gi, gjb, p, xA, xS, xN, r0C, r0N, r1C, r1S,
                          cu0A, cu1A, cu2A, cu3A);
                else
                    s2row(std::false_type{}, gi, gjb, p, xA, xS, xN, r0C, r0N, r1C, r1S,
                          cu0B, cu1B, cu2B, cu3B);
            }
        }
    }
}

extern "C" void kernel_launch(void* const* d_in, const int* in_sizes, int n_in,
                              void* d_out, int out_size, void* d_ws, size_t ws_size,
                              hipStream_t stream) {
    const float* y = (const float*)d_in[0];
    float* out = (float*)d_out;

    // ws layout: x2 fp32 buf0 | x2 fp32 buf1 | h-buf0 (6*CHW f16) | h-buf1
    float* x0 = (float*)d_ws;
    float* x1 = x0 + CHW;
    f16*   h0 = (f16*)(x1 + CHW);
    f16*   h1 = h0 + 6 * CHW;

    dim3 blk(192, 1, 1);
    dim3 grd(W / TW, H / TH, C);    // (8, 32, 3) = 768 blocks

    fused_it<0><<<grd, blk, 0, stream>>>(y, nullptr, nullptr, x0, h0, nullptr);
    for (int k = 2; k < N_IT; ++k) {
        const bool even = (k % 2 == 0);
        float* sx = even ? x0 : x1;  f16* sh = even ? h0 : h1;
        float* dx = even ? x1 : x0;  f16* dh = even ? h1 : h0;
        fused_it<1><<<grd, blk, 0, stream>>>(y, sx, sh, dx, dh, nullptr);
    }
    fused_it<2><<<grd, blk, 0, stream>>>(y, x0, h0, nullptr, nullptr, out);
}

// Round 12
// 331.276 us; speedup vs baseline: 1.6524x; 1.6524x over previous
//
#include <hip/hip_runtime.h>
#include <type_traits>

// TGV prox primal-dual, 30 iterations on (3,512,512) fp32.
// R12 = REVERT TO R10 (best verified: 331.8us). R11's row-pair restructure
// regressed 65%: holding the 14-segment u-stencil + doubled cu-stash live
// simultaneously blew the VGPR budget -> spills/occupancy collapse. Lesson:
// live-range width is the binding constraint; R9/R10's one-row-per-thread
// keeps ~10 loads live and consumes them promptly.
// Ladder: R4 bytes x0.6 -> -3.6%; R5 occ x2 -> -3.2%; R6 launches x0.53 -> 0%;
// R7 epochs/barriers halved -> 0%; R8 mask-free interior -> -6.6%;
// R9 interleaved state -> -12.6%; R10 TH16 + reg-reuse -> -1%; R11 row-pair
// -> +65% (REVERTED).
// Frozen: x2 fp32 / r,u fp16 interleaved ping-pong, single barrier,
// concurrent ring, rsqrt projections, SAFE/edge block split, 30 launches.
// R3: never grid.sync on this chip (~200us/iter).

#define H 512
#define W 512
#define C 3
#define HW (H * W)
#define CHW (C * H * W)
#define N_IT 30

#define TW 64
#define TH 16

#define TAU     0.01f
#define LAM2    0.15f
#define RHO     1.99f
#define SIGMA   1.3888888888888888f   /* 1/TAU/72 */
#define TL1     0.001f                /* TAU*LAM1 */
#define INV_1PT (1.0f / 1.01f)        /* 1/(1+TAU) */

// xbar/rbar planes rows -1..16 (18), cols lc = col+4 (col -4..67)
#define BROWS 18
#define BSTR  72

typedef _Float16 f16;
typedef __attribute__((ext_vector_type(4))) _Float16 h4;   //  8B
typedef __attribute__((ext_vector_type(8))) _Float16 h8;   // 16B

// h-buffer layout (f16 units): [0, 2*CHW) = r interleaved (r0,r1) per pixel;
//                              [2*CHW, 6*CHW) = u interleaved (u0..u3) per pixel.

template <int MODE> // 0 = first iter, 1 = middle, 2 = last (dst = d_out interleaved)
__global__ __launch_bounds__(384)
void fused_it(const float* __restrict__ y,
              const float* __restrict__ srcX,
              const f16*   __restrict__ srcH,
              float*       __restrict__ dstX,
              f16*         __restrict__ dstH,
              float*       __restrict__ outp)
{
    __shared__ float sb[3][BROWS][BSTR]; // 0=xbar 1=rbar0 2=rbar1

    const int tid = threadIdx.x;
    const int c   = blockIdx.z;
    const int i0  = blockIdx.y * TH;
    const int j0  = blockIdx.x * TW;
    const int cb  = c * HW;

    // block-uniform: all halo accesses in-image and all boundary conds true?
    const bool edge = (MODE == 0) ||
                      (blockIdx.x == 0) || (blockIdx.x == W / TW - 1) ||
                      (blockIdx.y == 0) || (blockIdx.y == H / TH - 1);

    const f16* rSrc = srcH;            // (r0,r1) pairs
    const f16* uSrc = srcH + 2 * CHW;  // (u0..u3) quads
    f16* rDst = dstH;
    f16* uDst = dstH ? dstH + 2 * CHW : nullptr;

    // kept in registers across the barrier for stage-2 (interior threads)
    float cu0[4], cu1[4], cu2[4], cu3[4];          // center u (old)
    float xbO[4], rb0O[4], rb1O[4];                // own xbar/rbar

    // ---- stage 1: x/r prox on a strip of 4 positions; xbar/rbar -> LDS ----
    auto strip1 = [&](auto SAFE_c, int rr, int s, bool interior) {
        constexpr bool SAFE = decltype(SAFE_c)::value;
        const int gi  = i0 + rr;
        const int gjb = j0 + s;
        const int p   = cb + gi * W + gjb;

        const bool rowC  = SAFE || ((unsigned)gi < H);
        const bool cMain = SAFE || ((unsigned)gjb < W);  // covers gjb..gjb+3 (4-aligned)
        const bool okC   = rowC && cMain;

        float yv[4], x2c[4], r0c[4], r1c[4];
        if (okC) {
            *(float4*)yv = *(const float4*)(y + p);
        } else {
            yv[0] = yv[1] = yv[2] = yv[3] = 0.f;
        }
        if (MODE != 0) {
            if (okC) {
                *(float4*)x2c = *(const float4*)(srcX + p);
                const h8 rv = *(const h8*)(rSrc + 2 * p);
                #pragma unroll
                for (int e = 0; e < 4; ++e) {
                    r0c[e] = (float)rv[2 * e];
                    r1c[e] = (float)rv[2 * e + 1];
                }
            } else {
                #pragma unroll
                for (int e = 0; e < 4; ++e) { x2c[e] = 0.f; r0c[e] = 0.f; r1c[e] = 0.f; }
            }
        }

        float t0c[4], t1c[4], t0n[4], t1w[4];
        if (MODE == 0) {
            #pragma unroll
            for (int e = 0; e < 4; ++e) {
                x2c[e] = yv[e]; r0c[e] = 0.f; r1c[e] = 0.f;
                t0c[e] = t1c[e] = t0n[e] = t1w[e] = 0.f;
            }
            if (interior) {
                #pragma unroll
                for (int e = 0; e < 4; ++e) { cu0[e] = cu1[e] = cu2[e] = cu3[e] = 0.f; }
            }
        } else {
            const bool rowN = SAFE || ((unsigned)(gi - 1) < H);
            const bool rowS = SAFE || ((unsigned)(gi + 1) < H);
            const bool cm1  = SAFE || ((unsigned)(gjb - 1) < W);
            const bool c4   = SAFE || ((unsigned)(gjb + 4) < W);
            const int pN = p - W, pS = p + W;

            auto L4 = [&](int pp, bool ok) -> h4 {
                h4 z = {}; if (ok) z = *(const h4*)(uSrc + 4 * pp); return z;
            };
            auto L8 = [&](int pp, bool ok) -> h8 {
                h8 z = {}; if (ok) z = *(const h8*)(uSrc + 4 * pp); return z;
            };
            // 10 segment loads on 3 row bases
            const h4 nA = L4(pN - 1, rowN && cm1);
            const h8 nB = L8(pN,     rowN && cMain);
            const h8 nC = L8(pN + 2, rowN && cMain);
            const h4 nD = L4(pN + 4, rowN && c4);
            const h4 cA = L4(p - 1,  rowC && cm1);
            const h8 cB = L8(p,      okC);
            const h8 cC = L8(p + 2,  okC);
            const h4 cD = L4(p + 4,  rowC && c4);
            const h8 sB = L8(pS,     rowS && cMain);
            const h8 sC = L8(pS + 2, rowS && cMain);

            const float u0c[4] = {(float)cB[0], (float)cB[4], (float)cC[0], (float)cC[4]};
            const float u1c[5] = {(float)cB[1], (float)cB[5], (float)cC[1], (float)cC[5], (float)cD[1]};
            const float u2r[6] = {(float)cA[2], (float)cB[2], (float)cB[6], (float)cC[2], (float)cC[6], (float)cD[2]};
            const float u3c[5] = {(float)cA[3], (float)cB[3], (float)cB[7], (float)cC[3], (float)cC[7]};
            const float u0n[4] = {(float)nB[0], (float)nB[4], (float)nC[0], (float)nC[4]};
            const float u1n[5] = {(float)nB[1], (float)nB[5], (float)nC[1], (float)nC[5], (float)nD[1]};
            const float u3n[5] = {(float)nA[3], (float)nB[3], (float)nB[7], (float)nC[3], (float)nC[7]};
            const float u0s[4] = {(float)sB[0], (float)sB[4], (float)sC[0], (float)sC[4]};

            if constexpr (SAFE) {
                #pragma unroll
                for (int e = 0; e < 4; ++e) {
                    t0c[e] = TAU * (u0c[e] - u0s[e] + u1c[e] - u1c[e + 1]);
                    t1c[e] = TAU * (u2r[e + 1] - u2r[e + 2] + u3n[e + 1] - u3c[e + 1]);
                    t0n[e] = TAU * (u0n[e] - u0c[e] + u1n[e] - u1n[e + 1]);
                    t1w[e] = TAU * (u2r[e] - u2r[e + 1] + u3n[e] - u3c[e]);
                }
            } else {
                const bool im0 = gi > 0, imHl = gi < H - 1;
                #pragma unroll
                for (int e = 0; e < 4; ++e) {
                    const int gj = gjb + e;
                    const bool jm0 = gj > 0;
                    t0c[e] = TAU * (u0c[e] - u0s[e] + (jm0 ? u1c[e] : 0.f) - u1c[e + 1]);
                    t1c[e] = TAU * (u2r[e + 1] - u2r[e + 2] + u3n[e + 1] - (imHl ? u3c[e + 1] : 0.f));
                    t0n[e] = im0 ? TAU * (u0n[e] - u0c[e] + (jm0 ? u1n[e] : 0.f) - u1n[e + 1]) : 0.f;
                    t1w[e] = jm0 ? TAU * (u2r[e] - u2r[e + 1] + u3n[e] - (imHl ? u3c[e] : 0.f)) : 0.f;
                }
            }
            if (interior) {
                #pragma unroll
                for (int e = 0; e < 4; ++e) {
                    cu0[e] = u0c[e]; cu1[e] = u1c[e];
                    cu2[e] = u2r[e + 1]; cu3[e] = u3c[e + 1];
                }
            }
        }

        float xnew[4], rn0[4], rn1[4], xb[4], rb0[4], rb1[4];
        {
            const bool imH = SAFE ? true : (gi < H - 1);
            #pragma unroll
            for (int e = 0; e < 4; ++e) {
                const int gj = gjb + e;
                const bool jmW = SAFE ? true : (gj < W - 1);
                const float nT  = t0n[e] - (imH ? t0c[e] : 0.f) + t1w[e] - (jmW ? t1c[e] : 0.f);
                const float xv  = (x2c[e] - nT + TAU * yv[e]) * INV_1PT;
                xb[e] = 2.f * xv - x2c[e];
                const float rp0 = r0c[e] + t0c[e];
                const float rp1 = r1c[e] + t1c[e];
                const float ss  = rp0 * rp0 + rp1 * rp1;
                const float f   = 1.f - fminf(TL1 * rsqrtf(ss), 1.f);
                const float rv0 = rp0 * f, rv1 = rp1 * f;
                rb0[e]  = 2.f * rv0 - r0c[e];
                rb1[e]  = 2.f * rv1 - r1c[e];
                xnew[e] = x2c[e] + RHO * (xv - x2c[e]);
                rn0[e]  = r0c[e] + RHO * (rv0 - r0c[e]);
                rn1[e]  = r1c[e] + RHO * (rv1 - r1c[e]);
            }
        }
        *(float4*)&sb[0][rr + 1][s + 4] = *(float4*)xb;
        *(float4*)&sb[1][rr + 1][s + 4] = *(float4*)rb0;
        *(float4*)&sb[2][rr + 1][s + 4] = *(float4*)rb1;

        if (interior) {
            // keep own xbar/rbar in registers for stage-2 (skip 3 ds_reads)
            #pragma unroll
            for (int e = 0; e < 4; ++e) {
                xbO[e] = xb[e]; rb0O[e] = rb0[e]; rb1O[e] = rb1[e];
            }
            if (MODE == 2) {
                *(float4*)(outp + p) = *(float4*)xnew;
                *(float4*)(outp + CHW + 2 * p)     = make_float4(rn0[0], rn1[0], rn0[1], rn1[1]);
                *(float4*)(outp + CHW + 2 * p + 4) = make_float4(rn0[2], rn1[2], rn0[3], rn1[3]);
            } else {
                *(float4*)(dstX + p) = *(float4*)xnew;
                h8 hr;
                #pragma unroll
                for (int e = 0; e < 4; ++e) {
                    hr[2 * e]     = (f16)rn0[e];
                    hr[2 * e + 1] = (f16)rn1[e];
                }
                *(h8*)(rDst + 2 * p) = hr;
            }
        }
    };

    auto ringmap = [&](int t, int& rr, int& s) {
        if (t < 18)      { rr = -1;      s = 4 * t - 4; }
        else if (t < 36) { rr = TH;      s = 4 * (t - 18) - 4; }
        else if (t < 36 + TH) { rr = t - 36;      s = -4; }
        else                  { rr = t - 36 - TH; s = TW; }
    };

    // stage 1: threads 0-255 interior (16 rows x 16 strips), threads 256-323
    // the 68 ring strips, all concurrent (different waves).
    if (!edge) {
        if (tid < 256) {
            strip1(std::true_type{}, tid >> 4, 4 * (tid & 15), true);
        } else if (tid < 256 + 36 + 2 * TH) {
            int rr, s; ringmap(tid - 256, rr, s);
            strip1(std::true_type{}, rr, s, false);
        }
    } else {
        if (tid < 256) {
            strip1(std::false_type{}, tid >> 4, 4 * (tid & 15), true);
        } else if (tid < 256 + 36 + 2 * TH) {
            int rr, s; ringmap(tid - 256, rr, s);
            strip1(std::false_type{}, rr, s, false);
        }
    }
    __syncthreads(); // the ONLY barrier: xbar/rbar handoff

    // ---- stage 2: u prox on interior; own xbar/rbar + center-u from regs ----
    auto stage2 = [&](auto SAFE_c) {
        constexpr bool SAFE = decltype(SAFE_c)::value;
        const int tx = tid & 15, ty = tid >> 4;
        const int gi  = i0 + ty;
        const int gjb = j0 + 4 * tx;
        const int lr  = ty + 1;
        const int lc  = 4 * tx + 4;
        float4 v;
        float xA[6], xS[6], xN[4], r0C[5], r0N[4], r1C[5], r1S[4];
        // true neighbor data from LDS (10 reads); own values from registers
        xA[0] = sb[0][lr][lc - 1];
        xA[1] = xbO[0]; xA[2] = xbO[1]; xA[3] = xbO[2]; xA[4] = xbO[3];
        xA[5] = sb[0][lr][lc + 4];
        xS[0] = sb[0][lr + 1][lc - 1];
        v = *(const float4*)&sb[0][lr + 1][lc]; xS[1]=v.x; xS[2]=v.y; xS[3]=v.z; xS[4]=v.w;
        xS[5] = sb[0][lr + 1][lc + 4];
        v = *(const float4*)&sb[0][lr - 1][lc]; xN[0]=v.x; xN[1]=v.y; xN[2]=v.z; xN[3]=v.w;
        r0C[0] = sb[1][lr][lc - 1];
        r0C[1] = rb0O[0]; r0C[2] = rb0O[1]; r0C[3] = rb0O[2]; r0C[4] = rb0O[3];
        v = *(const float4*)&sb[1][lr - 1][lc]; r0N[0]=v.x; r0N[1]=v.y; r0N[2]=v.z; r0N[3]=v.w;
        r1C[0] = sb[2][lr][lc - 1];
        r1C[1] = rb1O[0]; r1C[2] = rb1O[1]; r1C[3] = rb1O[2]; r1C[4] = rb1O[3];
        v = *(const float4*)&sb[2][lr + 1][lc]; r1S[0]=v.x; r1S[1]=v.y; r1S[2]=v.z; r1S[3]=v.w;

        const bool im0 = SAFE ? true : (gi > 0);
        const bool imH = SAFE ? true : (gi < H - 1);
        float un0[4], un1[4], un2[4], un3[4];
        #pragma unroll
        for (int e = 0; e < 4; ++e) {
            const int gj = gjb + e;
            const bool jm0 = SAFE ? true : (gj > 0);
            const bool jmW = SAFE ? true : (gj < W - 1);
            const float xC = xA[e + 1], xE = xA[e + 2], xW_ = xA[e];
            const float I0c = (imH ? xS[e + 1] - xC : 0.f) - r0C[e + 1];
            const float I0n = im0 ? (xC - xN[e] - r0N[e]) : 0.f;
            const float I0w = jm0 ? ((imH ? xS[e] - xW_ : 0.f) - r0C[e]) : 0.f;
            const float I1c = (jmW ? xE - xC : 0.f) - r1C[e + 1];
            const float I1w = jm0 ? (xC - xW_ - r1C[e]) : 0.f;
            const float I1s = imH ? ((jmW ? xS[e + 2] - xS[e + 1] : 0.f) - r1S[e]) : 0.f;
            const float g0 = I0c - I0n;
            const float g1 = jm0 ? (I0c - I0w) : 0.f;
            const float g2 = I1c - I1w;
            const float g3 = imH ? (I1s - I1c) : 0.f;
            const float up0 = cu0[e] + SIGMA * g0;
            const float up1 = cu1[e] + SIGMA * g1;
            const float up2 = cu2[e] + SIGMA * g2;
            const float up3 = cu3[e] + SIGMA * g3;
            const float ss  = up0 * up0 + up1 * up1 + up2 * up2 + up3 * up3;
            const float inv = fminf(LAM2 * rsqrtf(ss), 1.f);
            un0[e] = cu0[e] + RHO * (up0 * inv - cu0[e]);
            un1[e] = cu1[e] + RHO * (up1 * inv - cu1[e]);
            un2[e] = cu2[e] + RHO * (up2 * inv - cu2[e]);
            un3[e] = cu3[e] + RHO * (up3 * inv - cu3[e]);
        }
        const int p = cb + gi * W + gjb;
        if (MODE == 2) {
            #pragma unroll
            for (int e = 0; e < 4; ++e)
                *(float4*)(outp + 3 * CHW + 4 * (p + e)) =
                    make_float4(un0[e], un1[e], un2[e], un3[e]);
        } else {
            h8 w0, w1;
            #pragma unroll
            for (int e = 0; e < 2; ++e) {
                w0[4 * e + 0] = (f16)un0[e]; w0[4 * e + 1] = (f16)un1[e];
                w0[4 * e + 2] = (f16)un2[e]; w0[4 * e + 3] = (f16)un3[e];
            }
            #pragma unroll
            for (int e = 2; e < 4; ++e) {
                w1[4 * (e - 2) + 0] = (f16)un0[e]; w1[4 * (e - 2) + 1] = (f16)un1[e];
                w1[4 * (e - 2) + 2] = (f16)un2[e]; w1[4 * (e - 2) + 3] = (f16)un3[e];
            }
            *(h8*)(uDst + 4 * p)     = w0;
            *(h8*)(uDst + 4 * p + 8) = w1;
        }
    };

    if (tid < 256) {
        if (!edge) stage2(std::true_type{});
        else       stage2(std::false_type{});
    }
}

extern "C" void kernel_launch(void* const* d_in, const int* in_sizes, int n_in,
                              void* d_out, int out_size, void* d_ws, size_t ws_size,
                              hipStream_t stream) {
    const float* y = (const float*)d_in[0];
    float* out = (float*)d_out;

    // ws layout: x2 fp32 buf0 | x2 fp32 buf1 | h-buf0 (6*CHW f16) | h-buf1
    float* x0 = (float*)d_ws;
    float* x1 = x0 + CHW;
    f16*   h0 = (f16*)(x1 + CHW);
    f16*   h1 = h0 + 6 * CHW;

    dim3 blk(384, 1, 1);
    dim3 grd(W / TW, H / TH, C);    // (8, 32, 3) = 768 blocks = 3/CU, 18 waves/CU

    fused_it<0><<<grd, blk, 0, stream>>>(y, nullptr, nullptr, x0, h0, nullptr);
    for (int k = 2; k < N_IT; ++k) {
        const bool even = (k % 2 == 0);
        float* sx = even ? x0 : x1;  f16* sh = even ? h0 : h1;
        float* dx = even ? x1 : x0;  f16* dh = even ? h1 : h0;
        fused_it<1><<<grd, blk, 0, stream>>>(y, sx, sh, dx, dh, nullptr);
    }
    fused_it<2><<<grd, blk, 0, stream>>>(y, x0, h0, nullptr, nullptr, out);
}

// Round 13
// 299.395 us; speedup vs baseline: 1.8284x; 1.1065x over previous
//
#include <hip/hip_runtime.h>
#include <type_traits>

// TGV prox primal-dual, 30 iterations on (3,512,512) fp32.
// R13: LEAN 2-ITERATION FUSION (15 launches). R6 proved fusion-neutral while
// adding ~15-19% ring compute => per-launch fixed cost ~2-4us is real and was
// exactly cancelled by R6's fat (pre-diet) body. This fuses with the R9/R12
// instruction diet: per pair, phase A (s1 iter k, rows -3..18, u gathered
// DIRECT from global) -> sbA(xbar/rbar)+sbB(xnew/rnew); phase B (s2 iter k,
// rows -2..17) -> u_k in LDS (fp16, OOI pixels stored 0 to keep zero-padding
// semantics); phase C (s1 iter k+1, rows -1..16, u from LDS, x2/r from sbB)
// -> sbA overwrite + global x/r stores (iter-k x/r/u never touch global:
// write traffic halved, phases C/D have NO global-input latency); phase D
// (s2 iter k+1, interior) -> global u. Grid-stride per-task loops, no
// cross-task register stash (R11 lesson: live-range width is the binding
// constraint). Garbage domains (sbA/su cols -5/68 uninitialized) verified to
// reach only xbar cols {-4,-3,66,67}, which phase D never reads.
// Ladder: R4 -3.6%, R5 -3.2%, R6 0%, R7 0%, R8 -6.6%, R9 -12.6%, R10 -1%,
// R11 +65% (reverted), R12 = R10 = 331.3us.
// R3: never grid.sync on this chip (~200us/iter).

#define H 512
#define W 512
#define C 3
#define HW (H * W)
#define CHW (C * H * W)
#define NPAIR 15

#define TW 64
#define TH 16

#define TAU     0.01f
#define LAM2    0.15f
#define RHO     1.99f
#define SIGMA   1.3888888888888888f   /* 1/TAU/72 */
#define TL1     0.001f                /* TAU*LAM1 */
#define INV_1PT (1.0f / 1.01f)        /* 1/(1+TAU) */

// sbA: xbar/rbar, rows -3..18 (idx rr+3, 22), cols -5..68 (idx c+8, dim 78;
//      idx 0..2 and 76..77 pad so float4 bases (idx s+8, s%4==0) are 16B-aligned)
#define AR 22
#define AC 78
// sbB: xnew/rnew of iter k, rows -1..16 (idx rr+1, 18), cols -4..67 (idx c+4)
#define BR 18
#define BC 72
// su: u_k, 4xf16 per pixel, rows -2..17 (idx rr+2, 20), cols -5..68 (idx c+6,
//     dim 75; idx 0 pad so 16B stores land at (s+6)%2==0 boundaries)
#define UR 20
#define UC 75

typedef _Float16 f16;
typedef __attribute__((ext_vector_type(4))) _Float16 h4;   //  8B
typedef __attribute__((ext_vector_type(8))) _Float16 h8;   // 16B

// h-buffer layout (f16 units): [0, 2*CHW) = r interleaved (r0,r1) per pixel;
//                              [2*CHW, 6*CHW) = u interleaved (u0..u3) per pixel.

template <int MODE> // 0 = pair (1,2); 1 = middle pair; 2 = last pair (29,30)
__global__ __launch_bounds__(256)
void fused2(const float* __restrict__ y,
            const float* __restrict__ srcX,
            const f16*   __restrict__ srcH,
            float*       __restrict__ dstX,
            f16*         __restrict__ dstH,
            float*       __restrict__ outp)
{
    __shared__ float sbA[3][AR][AC];   // 20.6 KB
    __shared__ float sbB[3][BR][BC];   // 15.6 KB
    __shared__ f16   su[UR][UC][4];    // 11.7 KB

    const int tid = threadIdx.x;
    const int c   = blockIdx.z;
    const int i0  = blockIdx.y * TH;
    const int j0  = blockIdx.x * TW;
    const int cb  = c * HW;

    const bool edge = (MODE == 0) ||
                      (blockIdx.x == 0) || (blockIdx.x == W / TW - 1) ||
                      (blockIdx.y == 0) || (blockIdx.y == H / TH - 1);

    const f16* rSrc = srcH;            // (r0,r1) pairs
    const f16* uSrc = srcH + 2 * CHW;  // (u0..u3) quads
    f16* rDst = dstH;
    f16* uDst = dstH ? dstH + 2 * CHW : nullptr;

    // ---- stage-1 prox core (masks only when !SAFE) ----
    auto prox1 = [&](auto SAFE_c, int gi, int gjb,
                     const float* yv, const float* x2c, const float* r0c, const float* r1c,
                     const float* t0c, const float* t1c, const float* t0n, const float* t1w,
                     float* xb, float* rb0, float* rb1,
                     float* xn, float* rn0, float* rn1) {
        constexpr bool SAFE = decltype(SAFE_c)::value;
        const bool imH = SAFE ? true : (gi < H - 1);
        #pragma unroll
        for (int e = 0; e < 4; ++e) {
            const int gj = gjb + e;
            const bool jmW = SAFE ? true : (gj < W - 1);
            const float nT  = t0n[e] - (imH ? t0c[e] : 0.f) + t1w[e] - (jmW ? t1c[e] : 0.f);
            const float xv  = (x2c[e] - nT + TAU * yv[e]) * INV_1PT;
            xb[e] = 2.f * xv - x2c[e];
            const float rp0 = r0c[e] + t0c[e];
            const float rp1 = r1c[e] + t1c[e];
            const float ss  = rp0 * rp0 + rp1 * rp1;
            const float f   = 1.f - fminf(TL1 * rsqrtf(ss), 1.f);
            const float rv0 = rp0 * f, rv1 = rp1 * f;
            rb0[e] = 2.f * rv0 - r0c[e];
            rb1[e] = 2.f * rv1 - r1c[e];
            xn[e]  = x2c[e] + RHO * (xv - x2c[e]);
            rn0[e] = r0c[e] + RHO * (rv0 - r0c[e]);
            rn1[e] = r1c[e] + RHO * (rv1 - r1c[e]);
        }
    };

    // ---- t-terms from GLOBAL u (phase A; R12's proven gather) ----
    auto tGlob = [&](auto SAFE_c, int gi, int gjb, int p,
                     float* t0c, float* t1c, float* t0n, float* t1w) {
        constexpr bool SAFE = decltype(SAFE_c)::value;
        const bool rowC  = SAFE || ((unsigned)gi < H);
        const bool cMain = SAFE || ((unsigned)gjb < W);
        const bool okC   = rowC && cMain;
        const bool rowN = SAFE || ((unsigned)(gi - 1) < H);
        const bool rowS = SAFE || ((unsigned)(gi + 1) < H);
        const bool cm1  = SAFE || ((unsigned)(gjb - 1) < W);
        const bool c4   = SAFE || ((unsigned)(gjb + 4) < W);
        const int pN = p - W, pS = p + W;
        auto L4 = [&](int pp, bool ok) -> h4 { h4 z = {}; if (ok) z = *(const h4*)(uSrc + 4 * pp); return z; };
        auto L8 = [&](int pp, bool ok) -> h8 { h8 z = {}; if (ok) z = *(const h8*)(uSrc + 4 * pp); return z; };
        const h4 nA = L4(pN - 1, rowN && cm1);
        const h8 nB = L8(pN,     rowN && cMain);
        const h8 nC = L8(pN + 2, rowN && cMain);
        const h4 nD = L4(pN + 4, rowN && c4);
        const h4 cA = L4(p - 1,  rowC && cm1);
        const h8 cB = L8(p,      okC);
        const h8 cC = L8(p + 2,  okC);
        const h4 cD = L4(p + 4,  rowC && c4);
        const h8 sB = L8(pS,     rowS && cMain);
        const h8 sC = L8(pS + 2, rowS && cMain);

        const float u0c[4] = {(float)cB[0], (float)cB[4], (float)cC[0], (float)cC[4]};
        const float u1c[5] = {(float)cB[1], (float)cB[5], (float)cC[1], (float)cC[5], (float)cD[1]};
        const float u2r[6] = {(float)cA[2], (float)cB[2], (float)cB[6], (float)cC[2], (float)cC[6], (float)cD[2]};
        const float u3c[5] = {(float)cA[3], (float)cB[3], (float)cB[7], (float)cC[3], (float)cC[7]};
        const float u0n[4] = {(float)nB[0], (float)nB[4], (float)nC[0], (float)nC[4]};
        const float u1n[5] = {(float)nB[1], (float)nB[5], (float)nC[1], (float)nC[5], (float)nD[1]};
        const float u3n[5] = {(float)nA[3], (float)nB[3], (float)nB[7], (float)nC[3], (float)nC[7]};
        const float u0s[4] = {(float)sB[0], (float)sB[4], (float)sC[0], (float)sC[4]};

        if constexpr (SAFE) {
            #pragma unroll
            for (int e = 0; e < 4; ++e) {
                t0c[e] = TAU * (u0c[e] - u0s[e] + u1c[e] - u1c[e + 1]);
                t1c[e] = TAU * (u2r[e + 1] - u2r[e + 2] + u3n[e + 1] - u3c[e + 1]);
                t0n[e] = TAU * (u0n[e] - u0c[e] + u1n[e] - u1n[e + 1]);
                t1w[e] = TAU * (u2r[e] - u2r[e + 1] + u3n[e] - u3c[e]);
            }
        } else {
            const bool im0 = gi > 0, imHl = gi < H - 1;
            #pragma unroll
            for (int e = 0; e < 4; ++e) {
                const int gj = gjb + e;
                const bool jm0 = gj > 0;
                t0c[e] = TAU * (u0c[e] - u0s[e] + (jm0 ? u1c[e] : 0.f) - u1c[e + 1]);
                t1c[e] = TAU * (u2r[e + 1] - u2r[e + 2] + u3n[e + 1] - (imHl ? u3c[e + 1] : 0.f));
                t0n[e] = im0 ? TAU * (u0n[e] - u0c[e] + (jm0 ? u1n[e] : 0.f) - u1n[e + 1]) : 0.f;
                t1w[e] = jm0 ? TAU * (u2r[e] - u2r[e + 1] + u3n[e] - (imHl ? u3c[e] : 0.f)) : 0.f;
            }
        }
    };

    // ---- sbA stencil loader (shared by phases B and D) ----
    auto loadA = [&](int rr, int s,
                     float* xA, float* xS, float* xN,
                     float* r0C, float* r0N, float* r1C, float* r1S) {
        const int lr = rr + 3, lc = s + 8;
        float4 v;
        xA[0] = sbA[0][lr][lc - 1];
        v = *(const float4*)&sbA[0][lr][lc]; xA[1]=v.x; xA[2]=v.y; xA[3]=v.z; xA[4]=v.w;
        xA[5] = sbA[0][lr][lc + 4];
        xS[0] = sbA[0][lr + 1][lc - 1];
        v = *(const float4*)&sbA[0][lr + 1][lc]; xS[1]=v.x; xS[2]=v.y; xS[3]=v.z; xS[4]=v.w;
        xS[5] = sbA[0][lr + 1][lc + 4];
        v = *(const float4*)&sbA[0][lr - 1][lc]; xN[0]=v.x; xN[1]=v.y; xN[2]=v.z; xN[3]=v.w;
        r0C[0] = sbA[1][lr][lc - 1];
        v = *(const float4*)&sbA[1][lr][lc]; r0C[1]=v.x; r0C[2]=v.y; r0C[3]=v.z; r0C[4]=v.w;
        v = *(const float4*)&sbA[1][lr - 1][lc]; r0N[0]=v.x; r0N[1]=v.y; r0N[2]=v.z; r0N[3]=v.w;
        r1C[0] = sbA[2][lr][lc - 1];
        v = *(const float4*)&sbA[2][lr][lc]; r1C[1]=v.x; r1C[2]=v.y; r1C[3]=v.z; r1C[4]=v.w;
        v = *(const float4*)&sbA[2][lr + 1][lc]; r1S[0]=v.x; r1S[1]=v.y; r1S[2]=v.z; r1S[3]=v.w;
    };

    // ---- stage-2 core (shared by phases B and D) ----
    auto s2core = [&](auto SAFE_c, int gi, int gjb,
                      const float* xA, const float* xS, const float* xN,
                      const float* r0C, const float* r0N, const float* r1C, const float* r1S,
                      const float* cu0, const float* cu1, const float* cu2, const float* cu3,
                      float* un0, float* un1, float* un2, float* un3) {
        constexpr bool SAFE = decltype(SAFE_c)::value;
        const bool im0 = SAFE ? true : (gi > 0);
        const bool imH = SAFE ? true : (gi < H - 1);
        #pragma unroll
        for (int e = 0; e < 4; ++e) {
            const int gj = gjb + e;
            const bool jm0 = SAFE ? true : (gj > 0);
            const bool jmW = SAFE ? true : (gj < W - 1);
            const float xC = xA[e + 1], xE = xA[e + 2], xW_ = xA[e];
            const float I0c = (imH ? xS[e + 1] - xC : 0.f) - r0C[e + 1];
            const float I0n = im0 ? (xC - xN[e] - r0N[e]) : 0.f;
            const float I0w = jm0 ? ((imH ? xS[e] - xW_ : 0.f) - r0C[e]) : 0.f;
            const float I1c = (jmW ? xE - xC : 0.f) - r1C[e + 1];
            const float I1w = jm0 ? (xC - xW_ - r1C[e]) : 0.f;
            const float I1s = imH ? ((jmW ? xS[e + 2] - xS[e + 1] : 0.f) - r1S[e]) : 0.f;
            const float g0 = I0c - I0n;
            const float g1 = jm0 ? (I0c - I0w) : 0.f;
            const float g2 = I1c - I1w;
            const float g3 = imH ? (I1s - I1c) : 0.f;
            const float up0 = cu0[e] + SIGMA * g0;
            const float up1 = cu1[e] + SIGMA * g1;
            const float up2 = cu2[e] + SIGMA * g2;
            const float up3 = cu3[e] + SIGMA * g3;
            const float ss  = up0 * up0 + up1 * up1 + up2 * up2 + up3 * up3;
            const float inv = fminf(LAM2 * rsqrtf(ss), 1.f);
            un0[e] = cu0[e] + RHO * (up0 * inv - cu0[e]);
            un1[e] = cu1[e] + RHO * (up1 * inv - cu1[e]);
            un2[e] = cu2[e] + RHO * (up2 * inv - cu2[e]);
            un3[e] = cu3[e] + RHO * (up3 * inv - cu3[e]);
        }
    };

    // ================= phase A: stage-1 of iter k, rows -3..18 =================
    auto phaseA = [&](auto SAFE_c) {
        constexpr bool SAFE = decltype(SAFE_c)::value;
        for (int idx = tid; idx < AR * 18; idx += 256) {
            const int rw = idx / 18, rr = rw - 3;
            const int s  = 4 * (idx - rw * 18) - 4;
            const int gi = i0 + rr, gjb = j0 + s;
            const int p  = cb + gi * W + gjb;
            const bool rowC  = SAFE || ((unsigned)gi < H);
            const bool cMain = SAFE || ((unsigned)gjb < W);
            const bool okC   = rowC && cMain;

            float yv[4], x2c[4], r0c[4], r1c[4];
            if (okC) { *(float4*)yv = *(const float4*)(y + p); }
            else     { yv[0] = yv[1] = yv[2] = yv[3] = 0.f; }

            float t0c[4], t1c[4], t0n[4], t1w[4];
            if (MODE == 0) {
                #pragma unroll
                for (int e = 0; e < 4; ++e) {
                    x2c[e] = yv[e]; r0c[e] = 0.f; r1c[e] = 0.f;
                    t0c[e] = t1c[e] = t0n[e] = t1w[e] = 0.f;
                }
            } else {
                if (okC) {
                    *(float4*)x2c = *(const float4*)(srcX + p);
                    const h8 rv = *(const h8*)(rSrc + 2 * p);
                    #pragma unroll
                    for (int e = 0; e < 4; ++e) {
                        r0c[e] = (float)rv[2 * e];
                        r1c[e] = (float)rv[2 * e + 1];
                    }
                } else {
                    #pragma unroll
                    for (int e = 0; e < 4; ++e) { x2c[e] = 0.f; r0c[e] = 0.f; r1c[e] = 0.f; }
                }
                tGlob(SAFE_c, gi, gjb, p, t0c, t1c, t0n, t1w);
            }

            float xb[4], rb0[4], rb1[4], xn[4], rn0[4], rn1[4];
            prox1(SAFE_c, gi, gjb, yv, x2c, r0c, r1c, t0c, t1c, t0n, t1w,
                  xb, rb0, rb1, xn, rn0, rn1);

            *(float4*)&sbA[0][rr + 3][s + 8] = *(float4*)xb;
            *(float4*)&sbA[1][rr + 3][s + 8] = *(float4*)rb0;
            *(float4*)&sbA[2][rr + 3][s + 8] = *(float4*)rb1;
            if (rr >= -1 && rr <= 16) {
                *(float4*)&sbB[0][rr + 1][s + 4] = *(float4*)xn;
                *(float4*)&sbB[1][rr + 1][s + 4] = *(float4*)rn0;
                *(float4*)&sbB[2][rr + 1][s + 4] = *(float4*)rn1;
            }
            // no global stores: iter-k x/r live only in LDS
        }
    };

    // ================= phase B: stage-2 of iter k, rows -2..17 -> su ===========
    auto phaseB = [&](auto SAFE_c) {
        constexpr bool SAFE = decltype(SAFE_c)::value;
        for (int idx = tid; idx < UR * 18; idx += 256) {
            const int rw = idx / 18, rr = rw - 2;
            const int s  = 4 * (idx - rw * 18) - 4;
            const int gi = i0 + rr, gjb = j0 + s;
            const int p  = cb + gi * W + gjb;

            float xA[6], xS[6], xN[4], r0C[5], r0N[4], r1C[5], r1S[4];
            loadA(rr, s, xA, xS, xN, r0C, r0N, r1C, r1S);

            float cu0[4], cu1[4], cu2[4], cu3[4];
            if (MODE == 0) {
                #pragma unroll
                for (int e = 0; e < 4; ++e) { cu0[e] = cu1[e] = cu2[e] = cu3[e] = 0.f; }
            } else {
                const bool okC = SAFE || (((unsigned)gi < H) && ((unsigned)gjb < W));
                if (okC) {
                    const h8 a = *(const h8*)(uSrc + 4 * p);
                    const h8 b = *(const h8*)(uSrc + 4 * p + 8);
                    cu0[0]=(float)a[0]; cu1[0]=(float)a[1]; cu2[0]=(float)a[2]; cu3[0]=(float)a[3];
                    cu0[1]=(float)a[4]; cu1[1]=(float)a[5]; cu2[1]=(float)a[6]; cu3[1]=(float)a[7];
                    cu0[2]=(float)b[0]; cu1[2]=(float)b[1]; cu2[2]=(float)b[2]; cu3[2]=(float)b[3];
                    cu0[3]=(float)b[4]; cu1[3]=(float)b[5]; cu2[3]=(float)b[6]; cu3[3]=(float)b[7];
                } else {
                    #pragma unroll
                    for (int e = 0; e < 4; ++e) { cu0[e] = cu1[e] = cu2[e] = cu3[e] = 0.f; }
                }
            }

            float un0[4], un1[4], un2[4], un3[4];
            s2core(SAFE_c, gi, gjb, xA, xS, xN, r0C, r0N, r1C, r1S,
                   cu0, cu1, cu2, cu3, un0, un1, un2, un3);

            const int ur = rr + 2, uc = s + 6;
            if constexpr (SAFE) {
                h8 w0, w1;
                #pragma unroll
                for (int e = 0; e < 2; ++e) {
                    w0[4*e+0]=(f16)un0[e]; w0[4*e+1]=(f16)un1[e];
                    w0[4*e+2]=(f16)un2[e]; w0[4*e+3]=(f16)un3[e];
                }
                #pragma unroll
                for (int e = 2; e < 4; ++e) {
                    w1[4*(e-2)+0]=(f16)un0[e]; w1[4*(e-2)+1]=(f16)un1[e];
                    w1[4*(e-2)+2]=(f16)un2[e]; w1[4*(e-2)+3]=(f16)un3[e];
                }
                *(h8*)&su[ur][uc][0]     = w0;
                *(h8*)&su[ur][uc + 2][0] = w1;
            } else {
                // zero-padding semantics: out-of-image pixels MUST store 0
                #pragma unroll
                for (int e = 0; e < 4; ++e) {
                    const int gj = gjb + e;
                    const bool ok = ((unsigned)gi < H) && ((unsigned)gj < W);
                    h4 hv = {};
                    if (ok) { hv[0]=(f16)un0[e]; hv[1]=(f16)un1[e]; hv[2]=(f16)un2[e]; hv[3]=(f16)un3[e]; }
                    *(h4*)&su[ur][uc + e][0] = hv;
                }
            }
        }
    };

    // ================= phase C: stage-1 of iter k+1, rows -1..16 ===============
    auto phaseC = [&](auto SAFE_c) {
        constexpr bool SAFE = decltype(SAFE_c)::value;
        for (int idx = tid; idx < BR * 18; idx += 256) {
            const int rw = idx / 18, rr = rw - 1;
            const int s  = 4 * (idx - rw * 18) - 4;
            const int gi = i0 + rr, gjb = j0 + s;
            const int p  = cb + gi * W + gjb;
            const bool okC = SAFE || (((unsigned)gi < H) && ((unsigned)gjb < W));

            float yv[4];
            if (okC) { *(float4*)yv = *(const float4*)(y + p); }
            else     { yv[0] = yv[1] = yv[2] = yv[3] = 0.f; }

            float x2c[4], r0c[4], r1c[4];
            *(float4*)x2c = *(const float4*)&sbB[0][rr + 1][s + 4];
            *(float4*)r0c = *(const float4*)&sbB[1][rr + 1][s + 4];
            *(float4*)r1c = *(const float4*)&sbB[2][rr + 1][s + 4];

            // u_k gather from LDS (rows rr-1..rr+1 -> su rows rr+1..rr+3)
            h4 pN_[6], pC_[6], pS_[4];
            #pragma unroll
            for (int k = 0; k < 6; ++k) {
                pN_[k] = *(const h4*)&su[rr + 1][s + 5 + k][0];
                pC_[k] = *(const h4*)&su[rr + 2][s + 5 + k][0];
            }
            #pragma unroll
            for (int k = 0; k < 4; ++k)
                pS_[k] = *(const h4*)&su[rr + 3][s + 6 + k][0];

            const float u0c[4] = {(float)pC_[1][0], (float)pC_[2][0], (float)pC_[3][0], (float)pC_[4][0]};
            const float u1c[5] = {(float)pC_[1][1], (float)pC_[2][1], (float)pC_[3][1], (float)pC_[4][1], (float)pC_[5][1]};
            const float u2r[6] = {(float)pC_[0][2], (float)pC_[1][2], (float)pC_[2][2], (float)pC_[3][2], (float)pC_[4][2], (float)pC_[5][2]};
            const float u3c[5] = {(float)pC_[0][3], (float)pC_[1][3], (float)pC_[2][3], (float)pC_[3][3], (float)pC_[4][3]};
            const float u0n[4] = {(float)pN_[1][0], (float)pN_[2][0], (float)pN_[3][0], (float)pN_[4][0]};
            const float u1n[5] = {(float)pN_[1][1], (float)pN_[2][1], (float)pN_[3][1], (float)pN_[4][1], (float)pN_[5][1]};
            const float u3n[5] = {(float)pN_[0][3], (float)pN_[1][3], (float)pN_[2][3], (float)pN_[3][3], (float)pN_[4][3]};
            const float u0s[4] = {(float)pS_[0][0], (float)pS_[1][0], (float)pS_[2][0], (float)pS_[3][0]};

            float t0c[4], t1c[4], t0n[4], t1w[4];
            if constexpr (SAFE) {
                #pragma unroll
                for (int e = 0; e < 4; ++e) {
                    t0c[e] = TAU * (u0c[e] - u0s[e] + u1c[e] - u1c[e + 1]);
                    t1c[e] = TAU * (u2r[e + 1] - u2r[e + 2] + u3n[e + 1] - u3c[e + 1]);
                    t0n[e] = TAU * (u0n[e] - u0c[e] + u1n[e] - u1n[e + 1]);
                    t1w[e] = TAU * (u2r[e] - u2r[e + 1] + u3n[e] - u3c[e]);
                }
            } else {
                const bool im0 = gi > 0, imHl = gi < H - 1;
                #pragma unroll
                for (int e = 0; e < 4; ++e) {
                    const int gj = gjb + e;
                    const bool jm0 = gj > 0;
                    t0c[e] = TAU * (u0c[e] - u0s[e] + (jm0 ? u1c[e] : 0.f) - u1c[e + 1]);
                    t1c[e] = TAU * (u2r[e + 1] - u2r[e + 2] + u3n[e + 1] - (imHl ? u3c[e + 1] : 0.f));
                    t0n[e] = im0 ? TAU * (u0n[e] - u0c[e] + (jm0 ? u1n[e] : 0.f) - u1n[e + 1]) : 0.f;
                    t1w[e] = jm0 ? TAU * (u2r[e] - u2r[e + 1] + u3n[e] - (imHl ? u3c[e] : 0.f)) : 0.f;
                }
            }

            float xb[4], rb0[4], rb1[4], xn[4], rn0[4], rn1[4];
            prox1(SAFE_c, gi, gjb, yv, x2c, r0c, r1c, t0c, t1c, t0n, t1w,
                  xb, rb0, rb1, xn, rn0, rn1);

            *(float4*)&sbA[0][rr + 3][s + 8] = *(float4*)xb;
            *(float4*)&sbA[1][rr + 3][s + 8] = *(float4*)rb0;
            *(float4*)&sbA[2][rr + 3][s + 8] = *(float4*)rb1;

            if ((unsigned)rr < 16 && (unsigned)s < 64) { // interior strip
                if (MODE == 2) {
                    *(float4*)(outp + p) = *(float4*)xn;
                    *(float4*)(outp + CHW + 2 * p)     = make_float4(rn0[0], rn1[0], rn0[1], rn1[1]);
                    *(float4*)(outp + CHW + 2 * p + 4) = make_float4(rn0[2], rn1[2], rn0[3], rn1[3]);
                } else {
                    *(float4*)(dstX + p) = *(float4*)xn;
                    h8 hr;
                    #pragma unroll
                    for (int e = 0; e < 4; ++e) {
                        hr[2 * e]     = (f16)rn0[e];
                        hr[2 * e + 1] = (f16)rn1[e];
                    }
                    *(h8*)(rDst + 2 * p) = hr;
                }
            }
        }
    };

    // ---- run phases (sbA WAR hazards covered by the inter-phase barriers) ----
    if (!edge) phaseA(std::true_type{});  else phaseA(std::false_type{});
    __syncthreads();
    if (!edge) phaseB(std::true_type{});  else phaseB(std::false_type{});
    __syncthreads();
    if (!edge) phaseC(std::true_type{});  else phaseC(std::false_type{});
    __syncthreads();

    // ================= phase D: stage-2 of iter k+1, interior ==================
    {
        const int rr = tid >> 4;
        const int s  = 4 * (tid & 15);
        const int gi = i0 + rr, gjb = j0 + s;
        const int p  = cb + gi * W + gjb;

        float xA[6], xS[6], xN[4], r0C[5], r0N[4], r1C[5], r1S[4];
        loadA(rr, s, xA, xS, xN, r0C, r0N, r1C, r1S);

        float cu0[4], cu1[4], cu2[4], cu3[4];
        {
            const h8 a = *(const h8*)&su[rr + 2][s + 6][0];
            const h8 b = *(const h8*)&su[rr + 2][s + 8][0];
            cu0[0]=(float)a[0]; cu1[0]=(float)a[1]; cu2[0]=(float)a[2]; cu3[0]=(float)a[3];
            cu0[1]=(float)a[4]; cu1[1]=(float)a[5]; cu2[1]=(float)a[6]; cu3[1]=(float)a[7];
            cu0[2]=(float)b[0]; cu1[2]=(float)b[1]; cu2[2]=(float)b[2]; cu3[2]=(float)b[3];
            cu0[3]=(float)b[4]; cu1[3]=(float)b[5]; cu2[3]=(float)b[6]; cu3[3]=(float)b[7];
        }

        float un0[4], un1[4], un2[4], un3[4];
        if (!edge)
            s2core(std::true_type{},  gi, gjb, xA, xS, xN, r0C, r0N, r1C, r1S,
                   cu0, cu1, cu2, cu3, un0, un1, un2, un3);
        else
            s2core(std::false_type{}, gi, gjb, xA, xS, xN, r0C, r0N, r1C, r1S,
                   cu0, cu1, cu2, cu3, un0, un1, un2, un3);

        if (MODE == 2) {
            #pragma unroll
            for (int e = 0; e < 4; ++e)
                *(float4*)(outp + 3 * CHW + 4 * (p + e)) =
                    make_float4(un0[e], un1[e], un2[e], un3[e]);
        } else {
            h8 w0, w1;
            #pragma unroll
            for (int e = 0; e < 2; ++e) {
                w0[4*e+0]=(f16)un0[e]; w0[4*e+1]=(f16)un1[e];
                w0[4*e+2]=(f16)un2[e]; w0[4*e+3]=(f16)un3[e];
            }
            #pragma unroll
            for (int e = 2; e < 4; ++e) {
                w1[4*(e-2)+0]=(f16)un0[e]; w1[4*(e-2)+1]=(f16)un1[e];
                w1[4*(e-2)+2]=(f16)un2[e]; w1[4*(e-2)+3]=(f16)un3[e];
            }
            *(h8*)(uDst + 4 * p)     = w0;
            *(h8*)(uDst + 4 * p + 8) = w1;
        }
    }
}

extern "C" void kernel_launch(void* const* d_in, const int* in_sizes, int n_in,
                              void* d_out, int out_size, void* d_ws, size_t ws_size,
                              hipStream_t stream) {
    const float* y = (const float*)d_in[0];
    float* out = (float*)d_out;

    // ws layout: x2 fp32 buf0 | x2 fp32 buf1 | h-buf0 (6*CHW f16) | h-buf1
    float* x0 = (float*)d_ws;
    float* x1 = x0 + CHW;
    f16*   h0 = (f16*)(x1 + CHW);
    f16*   h1 = h0 + 6 * CHW;

    dim3 blk(256, 1, 1);
    dim3 grd(W / TW, H / TH, C);    // (8, 32, 3) = 768 blocks

    // 15 fused launches: pairs (1,2),(3,4),...,(29,30)
    fused2<0><<<grd, blk, 0, stream>>>(y, nullptr, nullptr, x0, h0, nullptr);
    for (int i = 1; i < NPAIR - 1; ++i) {
        const bool even = (i % 2 == 0);
        float* sx = even ? x1 : x0;  f16* sh = even ? h1 : h0;
        float* dx = even ? x0 : x1;  f16* dh = even ? h0 : h1;
        fused2<1><<<grd, blk, 0, stream>>>(y, sx, sh, dx, dh, nullptr);
    }
    // pair 15 (iters 29,30): src = dst of pair 14 (i=13, odd -> x1/h1)
    fused2<2><<<grd, blk, 0, stream>>>(y, x1, h1, nullptr, nullptr, out);
}